// Round 7
// baseline (351.457 us; speedup 1.0000x reference)
//
#include <hip/hip_runtime.h>
#include <hip/hip_bf16.h>

typedef _Float16 f16x8 __attribute__((ext_vector_type(8)));
typedef _Float16 f16x4 __attribute__((ext_vector_type(4)));
typedef float f32x4 __attribute__((ext_vector_type(4)));

#define B_SZ 64
#define T_SZ 2048
#define D_SZ 300
#define M_SZ (B_SZ * T_SZ)      // 131072
#define KP 320                   // padded K
#define NP 640                   // padded combined N (z: 0..299, o: 320..619)
#define NCHUNK 32
#define CLEN 64                  // T / NCHUNK

__device__ __forceinline__ void gld_lds16(const void* g, void* l) {
    __builtin_amdgcn_global_load_lds(
        (const __attribute__((address_space(1))) unsigned int*)g,
        (__attribute__((address_space(3))) unsigned int*)l,
        16, 0, 0);
}

__device__ __forceinline__ float fast_tanh(float x) {
    float e = __expf(2.0f * x);
    return 1.0f - 2.0f * __builtin_amdgcn_rcpf(e + 1.0f);
}

// ---- pack X fp32 [M,300] -> fp16 [M,320], vectorized, pad fused ----
__global__ void pack_x(const float* __restrict__ in, _Float16* __restrict__ out) {
    unsigned int i = blockIdx.x * 256u + threadIdx.x;   // grid covers M*80 exactly
    unsigned int row = i / 80;
    unsigned int kq = i - row * 80;
    if (kq < 75) {
        f32x4 v = *(const f32x4*)(in + (size_t)row * D_SZ + kq * 4);
        f16x4 h;
#pragma unroll
        for (int r = 0; r < 4; ++r) h[r] = (_Float16)v[r];
        *(f16x4*)(out + (size_t)row * KP + kq * 4) = h;
    } else {
        f16x4 z = {};
        *(f16x4*)(out + (size_t)row * KP + 300 + (kq - 75) * 4) = z;
    }
}

// ---- pack Wz/Wo fp32 [300,300] -> combined fp16 [640,320], zero-padded ----
__global__ void pack_w(const float* __restrict__ Wz, const float* __restrict__ Wo,
                       _Float16* __restrict__ W) {
    unsigned int i = blockIdx.x * 256u + threadIdx.x;
    if (i >= NP * KP) return;
    unsigned int n = i / KP;
    unsigned int k = i - n * KP;
    float v = 0.0f;
    if (k < D_SZ) {
        if (n < D_SZ) v = Wz[n * D_SZ + k];
        else if (n >= 320 && n < 320 + D_SZ) v = Wo[(n - 320) * D_SZ + k];
    }
    W[i] = (_Float16)v;
}

__global__ void pack_bias(const float* __restrict__ bz, const float* __restrict__ bo,
                          float* __restrict__ bias) {
    int n = threadIdx.x;
    float v = 0.0f;
    if (n < D_SZ) v = bz[n];
    else if (n >= 320 && n < 320 + D_SZ) v = bo[n - 320];
    bias[n] = v;
}

// ---- GEMM: C16[m][n] = tanh( sum_k X[m][k]*W[n][k] + bias[n] ), fp16 out ----
// 1-WAVE blocks (64 threads), 64x64 tile, BK=64 (exactly 5 K-steps, no tail).
// Barrier-free: single-buffered 16KB LDS, restage after frags are in regs.
// Latency hidden by ~10 independent waves/CU, all self-paced.
// LDS layout per operand: [ku][64 rows][32 k] f16, 64B rows, proven
// conflict-free swizzle u ^ ((row>>1)&3), staged via global_load_lds with
// pre-swizzled per-lane source (16 full lines per instruction).
__global__ __launch_bounds__(64, 4) void gemm_zo(const _Float16* __restrict__ X,
                                                 const _Float16* __restrict__ W,
                                                 const float* __restrict__ bias,
                                                 _Float16* __restrict__ C) {
    __shared__ _Float16 As[2][64 * 32];   // 8 KB  (ku halves)
    __shared__ _Float16 Bs[2][64 * 32];   // 8 KB

    const int lane = threadIdx.x;          // one wave
    // XCD-aware swizzle (20480 blocks, %8==0 -> bijective). bn inner: the 10
    // n-tiles of one bm run consecutively on one XCD (A-tile L2-hot, W hot).
    int g = blockIdx.x;
    int s = (g & 7) * (20480 / 8) + (g >> 3);
    int bm = s / 10;           // 2048 M-tiles
    int bn = s - bm * 10;      // 10 N-tiles

    const int l15 = lane & 15;
    const int kq = lane >> 4;

    // staging geometry: instr covers 16 rows x 64B; lane -> row j*16 + (lane>>2),
    // 16B unit (lane&2..) pre-swizzled source unit.
    const int r_in = lane >> 2;            // 0..15
    const int u4 = lane & 3;
    const int skey = (r_in >> 1) & 3;      // == ((lds_row>>1)&3) since j*16 keeps bits 1..2? (j*16>>1)&3==0
    const int ul = u4 ^ skey;              // pre-swizzled source 16B unit

    const _Float16* Abase = X + (size_t)(bm * 64) * KP;
    const _Float16* Bbase = W + (size_t)(bn * 64) * KP;

    auto stage = [&](int kt) {
#pragma unroll
        for (int ku = 0; ku < 2; ++ku) {
            int k0 = kt * 64 + ku * 32 + ul * 8;
#pragma unroll
            for (int j = 0; j < 4; ++j) {
                int row = j * 16 + r_in;
                gld_lds16(Abase + (size_t)row * KP + k0, &As[ku][j * 512]);
                gld_lds16(Bbase + (size_t)row * KP + k0, &Bs[ku][j * 512]);
            }
        }
    };

    f32x4 acc[4][4] = {};

    stage(0);

#pragma unroll 1
    for (int kt = 0; kt < 5; ++kt) {
        asm volatile("s_waitcnt vmcnt(0)" ::: "memory");   // tile kt landed
        __builtin_amdgcn_sched_barrier(0);

#pragma unroll
        for (int ku = 0; ku < 2; ++ku) {
            f16x8 af[4], bf[4];
#pragma unroll
            for (int ms = 0; ms < 4; ++ms) {
                int row = ms * 16 + l15;
                int u = kq ^ ((row >> 1) & 3);
                af[ms] = *(const f16x8*)&As[ku][row * 32 + u * 8];
            }
#pragma unroll
            for (int ns = 0; ns < 4; ++ns) {
                int row = ns * 16 + l15;
                int u = kq ^ ((row >> 1) & 3);
                bf[ns] = *(const f16x8*)&Bs[ku][row * 32 + u * 8];
            }
            asm volatile("s_waitcnt lgkmcnt(0)" ::: "memory");  // frags in regs
            __builtin_amdgcn_sched_barrier(0);

            if (ku == 1 && kt < 4) stage(kt + 1);   // safe: no other wave, frags read

            __builtin_amdgcn_s_setprio(1);
#pragma unroll
            for (int ms = 0; ms < 4; ++ms)
#pragma unroll
                for (int ns = 0; ns < 4; ++ns)
                    acc[ms][ns] = __builtin_amdgcn_mfma_f32_16x16x32_f16(bf[ns], af[ms], acc[ms][ns], 0, 0, 0);
            __builtin_amdgcn_s_setprio(0);
        }
    }

    // epilogue: swapped layout -> lane holds 4 consecutive n at one m.
    // m = mrow0 + ms*16 + l15; n = ncol0 + ns*16 + kq*4 + r
    const int mrow0 = bm * 64;
    const int ncol0 = bn * 64;
#pragma unroll
    for (int ns = 0; ns < 4; ++ns) {
        int nb = ncol0 + ns * 16 + kq * 4;
        f32x4 b4 = *(const f32x4*)&bias[nb];
#pragma unroll
        for (int ms = 0; ms < 4; ++ms) {
            int m = mrow0 + ms * 16 + l15;
            f16x4 v;
#pragma unroll
            for (int r = 0; r < 4; ++r)
                v[r] = (_Float16)fast_tanh(acc[ms][ns][r] + b4[r]);
            *(f16x4*)&C[(size_t)m * NP + nb] = v;
        }
    }
}

// ---- scan phase 1: per (b, chunk, d) compute affine (A = prod g, Bc) ----
__global__ void scan_p1(const float* __restrict__ gate, const _Float16* __restrict__ C,
                        float* __restrict__ Aout, float* __restrict__ Bout) {
    int b = blockIdx.x >> 5;
    int nc = blockIdx.x & 31;
    int d = threadIdx.x;
    if (d >= D_SZ) return;
    size_t base = (size_t)b * T_SZ + (size_t)nc * CLEN;
    const float* gp = gate + base * D_SZ + d;
    const _Float16* zp = C + base * NP + d;
    float A = 1.0f, Bc = 0.0f;
    for (int t = 0; t < CLEN; ++t) {
        float gv = gp[(size_t)t * D_SZ];
        float zv = (float)zp[(size_t)t * NP];
        A *= gv;
        Bc = gv * Bc + (1.0f - gv) * zv;
    }
    int o = (b * NCHUNK + nc) * D_SZ + d;
    Aout[o] = A;
    Bout[o] = Bc;
}

// ---- scan phase 2: sequential scan over the 32 chunk summaries ----
__global__ void scan_p2(const float* __restrict__ A, const float* __restrict__ Bc,
                        float* __restrict__ Cin) {
    int idx = blockIdx.x * 256 + threadIdx.x;
    if (idx >= B_SZ * D_SZ) return;
    int b = idx / D_SZ;
    int d = idx - b * D_SZ;
    float c = 0.0f;
    for (int nc = 0; nc < NCHUNK; ++nc) {
        int o = (b * NCHUNK + nc) * D_SZ + d;
        Cin[o] = c;
        c = A[o] * c + Bc[o];
    }
}

// ---- scan phase 3: replay chunk with correct c_in, write h = o * c ----
__global__ void scan_p3(const float* __restrict__ gate, const _Float16* __restrict__ C,
                        const float* __restrict__ Cin, float* __restrict__ out) {
    int b = blockIdx.x >> 5;
    int nc = blockIdx.x & 31;
    int d = threadIdx.x;
    if (d >= D_SZ) return;
    size_t base = (size_t)b * T_SZ + (size_t)nc * CLEN;
    const float* gp = gate + base * D_SZ + d;
    const _Float16* zp = C + base * NP + d;
    const _Float16* op = zp + 320;
    float* hp = out + base * D_SZ + d;
    float c = Cin[(b * NCHUNK + nc) * D_SZ + d];
    for (int t = 0; t < CLEN; ++t) {
        float gv = gp[(size_t)t * D_SZ];
        float zv = (float)zp[(size_t)t * NP];
        float ov = (float)op[(size_t)t * NP];
        c = gv * c + (1.0f - gv) * zv;
        hp[(size_t)t * D_SZ] = ov * c;
    }
}

extern "C" void kernel_launch(void* const* d_in, const int* in_sizes, int n_in,
                              void* d_out, int out_size, void* d_ws, size_t ws_size,
                              hipStream_t stream) {
    const float* gate = (const float*)d_in[0];
    const float* xin  = (const float*)d_in[1];
    const float* Wz   = (const float*)d_in[2];
    const float* bz   = (const float*)d_in[3];
    const float* Wo   = (const float*)d_in[4];
    const float* bo   = (const float*)d_in[5];
    float* out = (float*)d_out;

    char* ws = (char*)d_ws;
    _Float16* Xf16 = (_Float16*)(ws);                       // M*KP*2      = 83,886,080
    _Float16* C16  = (_Float16*)(ws + 83886080ull);         // M*NP*2      = 167,772,160
    _Float16* Wc   = (_Float16*)(ws + 251658240ull);        // NP*KP*2     = 409,600
    float*    bias = (float*)   (ws + 252067840ull);        // NP*4        = 2,560
    float*    Ach  = (float*)   (ws + 252070400ull);        // 64*32*300*4 = 2,457,600
    float*    Bch  = (float*)   (ws + 254528000ull);        // 2,457,600
    float*    Cin  = (float*)   (ws + 256985600ull);        // 2,457,600

    pack_x<<<(M_SZ * 80) / 256, 256, 0, stream>>>(xin, Xf16);
    pack_w<<<(NP * KP + 255) / 256, 256, 0, stream>>>(Wz, Wo, Wc);
    pack_bias<<<1, NP, 0, stream>>>(bz, bo, bias);

    gemm_zo<<<(M_SZ / 64) * (NP / 64), 64, 0, stream>>>(Xf16, Wc, bias, C16);

    scan_p1<<<B_SZ * NCHUNK, 320, 0, stream>>>(gate, C16, Ach, Bch);
    scan_p2<<<(B_SZ * D_SZ + 255) / 256, 256, 0, stream>>>(Ach, Bch, Cin);
    scan_p3<<<B_SZ * NCHUNK, 320, 0, stream>>>(gate, C16, Cin, out);
}